// Round 17
// baseline (121.275 us; speedup 1.0000x reference)
//
#include <hip/hip_runtime.h>

typedef unsigned short u16;
typedef unsigned int u32;
typedef __attribute__((ext_vector_type(8))) short short8;
typedef __attribute__((ext_vector_type(4))) float f32x4;
typedef __attribute__((ext_vector_type(4))) u32 u32x4;

#define AS1 __attribute__((address_space(1)))
#define AS3 __attribute__((address_space(3)))

__device__ __forceinline__ u16 f2bf(float f) {
  u32 u = __float_as_uint(f);
  u32 r = u + 0x7FFFu + ((u >> 16) & 1u);
  return (u16)(r >> 16);
}
__device__ __forceinline__ float bf2f(u16 b) {
  return __uint_as_float(((u32)b) << 16);
}
__device__ __forceinline__ u32 pack2(float a, float b) {
  return (u32)f2bf(a) | ((u32)f2bf(b) << 16);
}

__device__ __forceinline__ void gload_lds16(const void* g, void* l) {
  __builtin_amdgcn_global_load_lds((const AS1 u32*)g, (AS3 u32*)l, 16, 0, 0);
}

__device__ __forceinline__ f32x4 mfma16(short8 a, short8 b, f32x4 c) {
  return __builtin_amdgcn_mfma_f32_16x16x32_bf16(a, b, c, 0, 0, 0);
}

// ---------------- prep: weight transpose+cvt (z<4) and hidden cvt (z==4) ----------------
__global__ void prep(const float* __restrict__ W0, const float* __restrict__ W1,
                     const float* __restrict__ W2, const float* __restrict__ W3,
                     const float* __restrict__ hidden,
                     u16* __restrict__ T0, u16* __restrict__ T1,
                     u16* __restrict__ T2, u16* __restrict__ T3,
                     u16* __restrict__ hbf) {
  int z = blockIdx.z;
  int tx = threadIdx.x, ty = threadIdx.y;
  if (z == 4) {
    int lb = blockIdx.y * 32 + blockIdx.x;
    int tid = ty * 32 + tx;
    size_t base = (size_t)lb * 4096 + tid * 4;
    float4 v[4];
#pragma unroll
    for (int r = 0; r < 4; ++r) v[r] = *(const float4*)(hidden + base + r * 1024);
#pragma unroll
    for (int r = 0; r < 4; ++r) {
      uint2 p;
      p.x = pack2(v[r].x, v[r].y);
      p.y = pack2(v[r].z, v[r].w);
      *(uint2*)(hbf + base + r * 1024) = p;
    }
    return;
  }
  const float* W = z == 0 ? W0 : z == 1 ? W1 : z == 2 ? W2 : W3;
  u16* T = z == 0 ? T0 : z == 1 ? T1 : z == 2 ? T2 : T3;
  __shared__ float t[32][33];
  int bo = blockIdx.x * 32, bi = blockIdx.y * 32;
#pragma unroll
  for (int k = 0; k < 4; ++k)
    t[ty + k * 8][tx] = W[(size_t)(bi + ty + k * 8) * 1024 + bo + tx];
  __syncthreads();
#pragma unroll
  for (int k = 0; k < 4; ++k)
    T[(size_t)(bo + ty + k * 8) * 1024 + bi + tx] = f2bf(t[tx][ty + k * 8]);
}

// ---------------- fused QKV GEMM (BK=32, XCD-grouped, fused V^T epilogue) ----------------
// Round-15 structure; proj==2 writes V^T [bh][64][512] directly via a wave-local
// LDS transpose through the (dead) staging buffer. Unified smem so scratch
// aliasing is well-defined.
__global__ __launch_bounds__(256)
void gemm_qkv(const u16* __restrict__ A, const u16* __restrict__ Bt,
              const float* __restrict__ bq, const float* __restrict__ bk,
              const float* __restrict__ bv,
              u16* __restrict__ Qb, u16* __restrict__ Kb, u16* __restrict__ Vt) {
  const int K = 1024;
  __shared__ __align__(16) char smem[16384];
  u16(*As)[32] = (u16(*)[32])smem;             // [128][32]
  u16(*Bs)[32] = (u16(*)[32])(smem + 8192);    // [128][32]
  int lid = blockIdx.x;
  int xcd = lid & 7;
  int l = lid >> 3;                 // 0..95
  int by = xcd * 3 + (l >> 5);      // 0..23
  int bx = l & 31;
  int tid = threadIdx.x, wid = tid >> 6, lane = tid & 63;
  int wr = wid >> 1, wc = wid & 1;
  int brow = bx * 128, bcol = by * 128;
  int proj = bcol >> 10;
  int fr = lane & 15, fq = lane >> 4, k0 = fq * 8;
  int srow = lane >> 2;
  int sk = (lane & 3) * 8;

  f32x4 acc[4][4];
#pragma unroll
  for (int m = 0; m < 4; ++m)
#pragma unroll
    for (int n = 0; n < 4; ++n) acc[m][n] = (f32x4){0.f, 0.f, 0.f, 0.f};

  for (int kt = 0; kt < K; kt += 32) {
#pragma unroll
    for (int c = 0; c < 2; ++c) {
      int chunk = wid * 2 + c;
      gload_lds16(A + (size_t)(brow + chunk * 16 + srow) * K + kt + sk,
                  (char*)As + chunk * 1024);
      gload_lds16(Bt + (size_t)(bcol + chunk * 16 + srow) * K + kt + sk,
                  (char*)Bs + chunk * 1024);
    }
    __syncthreads();
    short8 afr[4], bfr[4];
#pragma unroll
    for (int m = 0; m < 4; ++m) afr[m] = *(const short8*)&As[wr * 64 + m * 16 + fr][k0];
#pragma unroll
    for (int n = 0; n < 4; ++n) bfr[n] = *(const short8*)&Bs[wc * 64 + n * 16 + fr][k0];
#pragma unroll
    for (int m = 0; m < 4; ++m)
#pragma unroll
      for (int n = 0; n < 4; ++n)
        acc[m][n] = mfma16(afr[m], bfr[n], acc[m][n]);
    __syncthreads();
  }

  if (proj == 2) {
    // fused V^T epilogue: per wave, transpose its 64-token x 64-d tile (one
    // head-half per wc) through wid-partitioned LDS scratch (staging dead).
    int hh = ((bcol & 1023) >> 6) + wc;
    int b = brow >> 9;
    int s0w = (brow & 511) + wr * 64;
    u16(*Tl)[64] = (u16(*)[64])(smem + wid * 4096);  // [32][64] per wave
#pragma unroll
    for (int nb = 0; nb < 2; ++nb) {
#pragma unroll
      for (int nn = 0; nn < 2; ++nn) {
        int n = nb * 2 + nn;
        int cc = (bcol & 1023) + wc * 64 + n * 16 + fr;
        float bias = bv[cc];
        int d_loc = nn * 16 + fr;
#pragma unroll
        for (int m = 0; m < 4; ++m)
#pragma unroll
          for (int j = 0; j < 4; ++j) {
            int s_loc = m * 16 + fq * 4 + j;
            int ss = (s_loc & 7) | ((((s_loc >> 3) ^ (d_loc & 7))) << 3);
            Tl[d_loc][ss] = f2bf(acc[m][n][j] + bias);
          }
      }
      // wave-local LDS order: reads after writes, no barrier needed
#pragma unroll
      for (int db = 0; db < 4; ++db) {
        int d_loc = db * 8 + (lane >> 3);
        int sg = lane & 7;
        short8 v = *(const short8*)&Tl[d_loc][(sg ^ (d_loc & 7)) << 3];
        *(short8*)(Vt + ((size_t)(b * 16 + hh) * 64 + nb * 32 + d_loc) * 512 +
                   s0w + sg * 8) = v;
      }
    }
    return;
  }

  const float* bp = proj == 0 ? bq : bk;
  u16* outp = proj == 0 ? Qb : Kb;
#pragma unroll
  for (int m = 0; m < 4; ++m)
#pragma unroll
    for (int n = 0; n < 4; ++n)
#pragma unroll
      for (int j = 0; j < 4; ++j) {
        int r = brow + wr * 64 + m * 16 + fq * 4 + j;
        int c = bcol + wc * 64 + n * 16 + fr;
        int cc = c & 1023;
        float v = acc[m][n][j] + bp[cc];
        int b = r >> 9, s = r & 511;
        int hh = cc >> 6, d = cc & 63;
        size_t o = (((size_t)(b * 16 + hh)) * 512 + s) * 64 + d;
        outp[o] = f2bf(v);
      }
}

// ---------------- out-proj GEMM (XCD-grouped 1D grid, 512 blocks) ----------------
__global__ __launch_bounds__(256)
void gemm_out(const u16* __restrict__ A, const u16* __restrict__ Bt,
              const float* __restrict__ bias, const float* __restrict__ resid,
              float* __restrict__ outf) {
  const int K = 1024;
  __shared__ __align__(16) u16 As[64][32];
  __shared__ __align__(16) u16 Bs[128][32];
  int xcd = blockIdx.x & 7;
  int l = blockIdx.x >> 3;          // 0..63
  int tid = threadIdx.x, wid = tid >> 6, lane = tid & 63;
  int wr = wid >> 1, wc = wid & 1;
  int brow = l * 64, bcol = xcd * 128;
  int fr = lane & 15, fq = lane >> 4, k0 = fq * 8;
  int srow = lane >> 2;
  int sk = (lane & 3) * 8;

  f32x4 acc[2][4];
#pragma unroll
  for (int m = 0; m < 2; ++m)
#pragma unroll
    for (int n = 0; n < 4; ++n) acc[m][n] = (f32x4){0.f, 0.f, 0.f, 0.f};

  for (int kt = 0; kt < K; kt += 32) {
#pragma unroll
    for (int c = 0; c < 3; ++c) {
      int chunk = wid * 3 + c;
      if (chunk < 4)
        gload_lds16(A + (size_t)(brow + chunk * 16 + srow) * K + kt + sk,
                    (char*)As + chunk * 1024);
      else
        gload_lds16(Bt + (size_t)(bcol + (chunk - 4) * 16 + srow) * K + kt + sk,
                    (char*)Bs + (chunk - 4) * 1024);
    }
    __syncthreads();
    short8 afr[2], bfr[4];
#pragma unroll
    for (int m = 0; m < 2; ++m) afr[m] = *(const short8*)&As[wr * 32 + m * 16 + fr][k0];
#pragma unroll
    for (int n = 0; n < 4; ++n) bfr[n] = *(const short8*)&Bs[wc * 64 + n * 16 + fr][k0];
#pragma unroll
    for (int m = 0; m < 2; ++m)
#pragma unroll
      for (int n = 0; n < 4; ++n)
        acc[m][n] = mfma16(afr[m], bfr[n], acc[m][n]);
    __syncthreads();
  }

#pragma unroll
  for (int m = 0; m < 2; ++m)
#pragma unroll
    for (int n = 0; n < 4; ++n)
#pragma unroll
      for (int j = 0; j < 4; ++j) {
        int r = brow + wr * 32 + m * 16 + fq * 4 + j;
        int c = bcol + wc * 64 + n * 16 + fr;
        float v = acc[m][n][j] + bias[c] + resid[(size_t)r * 1024 + c];
        outf[(size_t)r * 1024 + c] = v;
      }
}

// ---------------- attention: LDS-resident K/V via global_load_lds (pre-swizzled src) ----------------
// grid 512 x 256 thr (2 blocks/CU), XCD-grouped. As round 15.
__global__ __launch_bounds__(256, 2)
void attention(const u16* __restrict__ Q, const u16* __restrict__ K,
               const u16* __restrict__ Vt, const float* __restrict__ mask,
               float* __restrict__ score_out, u16* __restrict__ ctx) {
  const int S = 512, DH = 64;
  int bid = blockIdx.x;
  int xcd = bid & 7;
  int rest = bid >> 3;                 // 0..63
  int qq = rest & 3;                   // q-quarter
  int bh = xcd * 16 + (rest >> 2);     // XCD owns 16 bh
  int b = bh >> 4, h = bh & 15;
  int tid = threadIdx.x;
  int wid = tid >> 6, lane = tid & 63;
  int fr = lane & 15, fq = lane >> 4, k0e = fq * 8;
  int qbase = qq * 128 + wid * 32;

  const u16* Kp = K + (size_t)bh * S * DH;
  const u16* Vp = Vt + (size_t)bh * DH * S;
  const float* mrow = mask + b * S;

  __shared__ __align__(16) u16 Kl[256][64];   // phase keys, row-XOR-swizzled
  __shared__ __align__(16) u16 Vl[64][256];   // V^T phase cols, row-XOR-swizzled

  short8 af[2][2];
#pragma unroll
  for (int st = 0; st < 2; ++st) {
    const u16* Qp = Q + ((size_t)bh * S + qbase + st * 16 + fr) * DH;
    af[st][0] = *(const short8*)(Qp + k0e);
    af[st][1] = *(const short8*)(Qp + 32 + k0e);
  }

  float rsum[2] = {0.f, 0.f};
  f32x4 cacc[2][4];
#pragma unroll
  for (int st = 0; st < 2; ++st)
#pragma unroll
    for (int n = 0; n < 4; ++n) cacc[st][n] = (f32x4){0.f, 0.f, 0.f, 0.f};

  int hi = fq >> 1;
  int srcb = ((fq & 1) << 5) | fr;

#pragma unroll
  for (int p = 0; p < 2; ++p) {
    u32 mreg[16][2];
#pragma unroll
    for (int nb8 = 0; nb8 < 16; ++nb8) {
      float4 mv = *(const float4*)(mrow + p * 256 + nb8 * 16 + fq * 4);
      mreg[nb8][0] = pack2(mv.x * -10000.f, mv.y * -10000.f);
      mreg[nb8][1] = pack2(mv.z * -10000.f, mv.w * -10000.f);
    }
#pragma unroll
    for (int i = 0; i < 8; ++i) {
      int c = i * 256 + tid;
      int row = c >> 3, ch8 = c & 7;
      const u16* src = Kp + (size_t)(p * 256 + row) * 64 + 8 * (ch8 ^ (row & 7));
      gload_lds16(src, (char*)Kl + (i * 256 + wid * 64) * 16);
    }
#pragma unroll
    for (int i = 0; i < 8; ++i) {
      int c = i * 256 + tid;
      int d = c >> 5, ch = c & 31;
      const u16* src = Vp + (size_t)d * 512 + p * 256 + 8 * (ch ^ (d & 7));
      gload_lds16(src, (char*)Vl + (i * 256 + wid * 64) * 16);
    }
    __syncthreads();

#pragma unroll
    for (int st = 0; st < 2; ++st) {
      float* srow = score_out + ((size_t)(bh * 512 + qbase + st * 16 + fr)) * 512 + p * 256;
      u32 pk[16][2];
      __builtin_amdgcn_s_setprio(1);
#pragma unroll
      for (int nb8 = 0; nb8 < 16; ++nb8) {
        int r = nb8 * 16 + fr;
        int sw = (r & 7) << 3;
        short8 kf0 = *(const short8*)&Kl[r][k0e ^ sw];
        short8 kf1 = *(const short8*)&Kl[r][(32 + k0e) ^ sw];
        f32x4 a = (f32x4){0.f, 0.f, 0.f, 0.f};
        a = mfma16(kf0, af[st][0], a);
        a = mfma16(kf1, af[st][1], a);
        f32x4 s4;
        s4[0] = a[0] * 0.125f + bf2f((u16)(mreg[nb8][0] & 0xffff));
        s4[1] = a[1] * 0.125f + bf2f((u16)(mreg[nb8][0] >> 16));
        s4[2] = a[2] * 0.125f + bf2f((u16)(mreg[nb8][1] & 0xffff));
        s4[3] = a[3] * 0.125f + bf2f((u16)(mreg[nb8][1] >> 16));
        *(f32x4*)(srow + nb8 * 16 + fq * 4) = s4;
        float p0 = __expf(s4[0]);
        float p1 = __expf(s4[1]);
        float p2 = __expf(s4[2]);
        float p3 = __expf(s4[3]);
        rsum[st] += (p0 + p1) + (p2 + p3);
        pk[nb8][0] = pack2(p0, p1);
        pk[nb8][1] = pack2(p2, p3);
      }
#pragma unroll
      for (int ks = 0; ks < 8; ++ks) {
        u32 s0 = hi ? pk[2 * ks + 1][0] : pk[2 * ks][0];
        u32 s1 = hi ? pk[2 * ks + 1][1] : pk[2 * ks][1];
        u32x4 tv;
        tv.x = (u32)__shfl((int)s0, srcb, 64);
        tv.y = (u32)__shfl((int)s1, srcb, 64);
        tv.z = (u32)__shfl((int)s0, srcb + 16, 64);
        tv.w = (u32)__shfl((int)s1, srcb + 16, 64);
        short8 pa = __builtin_bit_cast(short8, tv);
        int kg = ks * 32 + k0e;
#pragma unroll
        for (int n = 0; n < 4; ++n) {
          int d = n * 16 + fr;
          short8 vf = *(const short8*)&Vl[d][kg ^ ((d & 7) << 3)];
          cacc[st][n] = mfma16(pa, vf, cacc[st][n]);
        }
      }
      __builtin_amdgcn_s_setprio(0);
    }
    __syncthreads();
  }

#pragma unroll
  for (int st = 0; st < 2; ++st) {
    rsum[st] += __shfl_xor(rsum[st], 16, 64);
    rsum[st] += __shfl_xor(rsum[st], 32, 64);
    float inv = 1.0f / rsum[st];
#pragma unroll
    for (int j = 0; j < 4; ++j) {
      float invj = __shfl(inv, (lane & 48) | ((fq * 4 + j) & 15), 64);
      int q = qbase + st * 16 + fq * 4 + j;
#pragma unroll
      for (int n = 0; n < 4; ++n) {
        float v = cacc[st][n][j] * invj;
        int d = n * 16 + fr;
        ctx[((size_t)(b * 512 + q)) * 1024 + h * 64 + d] = f2bf(v);
      }
    }
  }
}

// ---------------- LayerNorm ----------------
__global__ __launch_bounds__(256)
void ln_kernel(const float* __restrict__ x, const float* __restrict__ g,
               const float* __restrict__ be, float* __restrict__ out) {
  int row = blockIdx.x, t = threadIdx.x;
  const float4* xr = (const float4*)(x + (size_t)row * 1024);
  float4 v = xr[t];
  float s = v.x + v.y + v.z + v.w;
  float s2 = v.x * v.x + v.y * v.y + v.z * v.z + v.w * v.w;
#pragma unroll
  for (int o = 1; o < 64; o <<= 1) {
    s += __shfl_xor(s, o, 64);
    s2 += __shfl_xor(s2, o, 64);
  }
  __shared__ float ls[4], ls2[4];
  int w = t >> 6;
  if ((t & 63) == 0) { ls[w] = s; ls2[w] = s2; }
  __syncthreads();
  float S = ls[0] + ls[1] + ls[2] + ls[3];
  float S2 = ls2[0] + ls2[1] + ls2[2] + ls2[3];
  float mu = S * (1.0f / 1024.0f);
  float var = S2 * (1.0f / 1024.0f) - mu * mu;
  float r = rsqrtf(var + 1e-5f);
  float4 gv = ((const float4*)g)[t];
  float4 bv = ((const float4*)be)[t];
  float4 o4;
  o4.x = gv.x * (v.x - mu) * r + bv.x;
  o4.y = gv.y * (v.y - mu) * r + bv.y;
  o4.z = gv.z * (v.z - mu) * r + bv.z;
  o4.w = gv.w * (v.w - mu) * r + bv.w;
  ((float4*)(out + (size_t)row * 1024))[t] = o4;
}

// ---------------- launch ----------------
extern "C" void kernel_launch(void* const* d_in, const int* in_sizes, int n_in,
                              void* d_out, int out_size, void* d_ws, size_t ws_size,
                              hipStream_t stream) {
  const float* hidden = (const float*)d_in[0];
  const float* mask   = (const float*)d_in[1];
  const float* Wq = (const float*)d_in[2];  const float* bq = (const float*)d_in[3];
  const float* Wk = (const float*)d_in[4];  const float* bk = (const float*)d_in[5];
  const float* Wv = (const float*)d_in[6];  const float* bv = (const float*)d_in[7];
  const float* Wo = (const float*)d_in[8];  const float* bo = (const float*)d_in[9];
  const float* gamma = (const float*)d_in[10];
  const float* beta  = (const float*)d_in[11];

  float* out = (float*)d_out;
  float* attn_out = out + 4194304;  // [B][H][S][S]

  char* ws = (char*)d_ws;
  u16* hbf    = (u16*)(ws);                 // [4096][1024] bf16
  u16* WqkvT  = (u16*)(ws + 8388608);       // [3072][1024] bf16 (fused)
  u16* WoT    = (u16*)(ws + 14680064);      // [1024][1024] bf16
  u16* Qb     = (u16*)(ws + 16777216);      // [B][H][S][DH]
  u16* Kb     = (u16*)(ws + 25165824);      // [B][H][S][DH]
  u16* Vt     = (u16*)(ws + 41943040);      // [B][H][DH][S] (written by gemm_qkv)
  u16* ctx    = (u16*)(ws + 50331648);      // [4096][1024]
  float* xres = (float*)(ws + 16777216);    // fp32, reuses Qb/Kb (dead after attention)

  prep<<<dim3(32, 32, 5), dim3(32, 8), 0, stream>>>(
      Wq, Wk, Wv, Wo, hidden,
      WqkvT, WqkvT + 1048576, WqkvT + 2097152, WoT, hbf);
  gemm_qkv<<<768, 256, 0, stream>>>(hbf, WqkvT, bq, bk, bv, Qb, Kb, Vt);
  attention<<<512, 256, 0, stream>>>(Qb, Kb, Vt, mask, attn_out, ctx);
  gemm_out<<<512, 256, 0, stream>>>(ctx, WoT, bo, hidden, xres);
  ln_kernel<<<4096, 256, 0, stream>>>(xres, gamma, beta, out);
}

// Round 18
// 109.840 us; speedup vs baseline: 1.1041x; 1.1041x over previous
//
#include <hip/hip_runtime.h>

typedef unsigned short u16;
typedef unsigned int u32;
typedef __attribute__((ext_vector_type(8))) short short8;
typedef __attribute__((ext_vector_type(4))) float f32x4;
typedef __attribute__((ext_vector_type(4))) u32 u32x4;

#define AS1 __attribute__((address_space(1)))
#define AS3 __attribute__((address_space(3)))

__device__ __forceinline__ u16 f2bf(float f) {
  u32 u = __float_as_uint(f);
  u32 r = u + 0x7FFFu + ((u >> 16) & 1u);
  return (u16)(r >> 16);
}
__device__ __forceinline__ float bf2f(u16 b) {
  return __uint_as_float(((u32)b) << 16);
}
__device__ __forceinline__ u32 pack2(float a, float b) {
  return (u32)f2bf(a) | ((u32)f2bf(b) << 16);
}

__device__ __forceinline__ void gload_lds16(const void* g, void* l) {
  __builtin_amdgcn_global_load_lds((const AS1 u32*)g, (AS3 u32*)l, 16, 0, 0);
}

__device__ __forceinline__ f32x4 mfma16(short8 a, short8 b, f32x4 c) {
  return __builtin_amdgcn_mfma_f32_16x16x32_bf16(a, b, c, 0, 0, 0);
}

// ---------------- prep: weight transpose+cvt (z<4) and hidden cvt (z==4) ----------------
__global__ void prep(const float* __restrict__ W0, const float* __restrict__ W1,
                     const float* __restrict__ W2, const float* __restrict__ W3,
                     const float* __restrict__ hidden,
                     u16* __restrict__ T0, u16* __restrict__ T1,
                     u16* __restrict__ T2, u16* __restrict__ T3,
                     u16* __restrict__ hbf) {
  int z = blockIdx.z;
  int tx = threadIdx.x, ty = threadIdx.y;
  if (z == 4) {
    int lb = blockIdx.y * 32 + blockIdx.x;
    int tid = ty * 32 + tx;
    size_t base = (size_t)lb * 4096 + tid * 4;
    float4 v[4];
#pragma unroll
    for (int r = 0; r < 4; ++r) v[r] = *(const float4*)(hidden + base + r * 1024);
#pragma unroll
    for (int r = 0; r < 4; ++r) {
      uint2 p;
      p.x = pack2(v[r].x, v[r].y);
      p.y = pack2(v[r].z, v[r].w);
      *(uint2*)(hbf + base + r * 1024) = p;
    }
    return;
  }
  const float* W = z == 0 ? W0 : z == 1 ? W1 : z == 2 ? W2 : W3;
  u16* T = z == 0 ? T0 : z == 1 ? T1 : z == 2 ? T2 : T3;
  __shared__ float t[32][33];
  int bo = blockIdx.x * 32, bi = blockIdx.y * 32;
#pragma unroll
  for (int k = 0; k < 4; ++k)
    t[ty + k * 8][tx] = W[(size_t)(bi + ty + k * 8) * 1024 + bo + tx];
  __syncthreads();
#pragma unroll
  for (int k = 0; k < 4; ++k)
    T[(size_t)(bo + ty + k * 8) * 1024 + bi + tx] = f2bf(t[tx][ty + k * 8]);
}

// V [bh][512][64] -> Vt [bh][64][512] (bf16)
__global__ void vtrans(const u16* __restrict__ V, u16* __restrict__ Vt) {
  __shared__ u16 t[32][33];
  int bh = blockIdx.z;
  int s0 = blockIdx.x * 32, d0 = blockIdx.y * 32;
  int tx = threadIdx.x, ty = threadIdx.y;
  const u16* src = V + ((size_t)bh * 512 + s0) * 64 + d0;
#pragma unroll
  for (int k = 0; k < 4; ++k)
    t[ty + k * 8][tx] = src[(size_t)(ty + k * 8) * 64 + tx];
  __syncthreads();
  u16* dst = Vt + ((size_t)bh * 64 + d0) * 512 + s0;
#pragma unroll
  for (int k = 0; k < 4; ++k)
    dst[(size_t)(ty + k * 8) * 512 + tx] = t[tx][ty + k * 8];
}

// ---------------- fused QKV GEMM (XCD-grouped 1D grid, 768 blocks) ----------------
__global__ __launch_bounds__(256)
void gemm_qkv(const u16* __restrict__ A, const u16* __restrict__ Bt,
              const float* __restrict__ bq, const float* __restrict__ bk,
              const float* __restrict__ bv,
              u16* __restrict__ Qb, u16* __restrict__ Kb, u16* __restrict__ Vb) {
  const int K = 1024;
  __shared__ __align__(16) u16 As[128][32];
  __shared__ __align__(16) u16 Bs[128][32];
  int lid = blockIdx.x;
  int xcd = lid & 7;
  int l = lid >> 3;                 // 0..95
  int by = xcd * 3 + (l >> 5);      // 0..23
  int bx = l & 31;
  int tid = threadIdx.x, wid = tid >> 6, lane = tid & 63;
  int wr = wid >> 1, wc = wid & 1;
  int brow = bx * 128, bcol = by * 128;
  int proj = bcol >> 10;
  int fr = lane & 15, fq = lane >> 4, k0 = fq * 8;
  int srow = lane >> 2;
  int sk = (lane & 3) * 8;

  f32x4 acc[4][4];
#pragma unroll
  for (int m = 0; m < 4; ++m)
#pragma unroll
    for (int n = 0; n < 4; ++n) acc[m][n] = (f32x4){0.f, 0.f, 0.f, 0.f};

  for (int kt = 0; kt < K; kt += 32) {
#pragma unroll
    for (int c = 0; c < 2; ++c) {
      int chunk = wid * 2 + c;
      gload_lds16(A + (size_t)(brow + chunk * 16 + srow) * K + kt + sk,
                  (char*)As + chunk * 1024);
      gload_lds16(Bt + (size_t)(bcol + chunk * 16 + srow) * K + kt + sk,
                  (char*)Bs + chunk * 1024);
    }
    __syncthreads();
    short8 afr[4], bfr[4];
#pragma unroll
    for (int m = 0; m < 4; ++m) afr[m] = *(const short8*)&As[wr * 64 + m * 16 + fr][k0];
#pragma unroll
    for (int n = 0; n < 4; ++n) bfr[n] = *(const short8*)&Bs[wc * 64 + n * 16 + fr][k0];
#pragma unroll
    for (int m = 0; m < 4; ++m)
#pragma unroll
      for (int n = 0; n < 4; ++n)
        acc[m][n] = mfma16(afr[m], bfr[n], acc[m][n]);
    __syncthreads();
  }

  const float* bp = proj == 0 ? bq : proj == 1 ? bk : bv;
  u16* outp = proj == 0 ? Qb : proj == 1 ? Kb : Vb;
#pragma unroll
  for (int m = 0; m < 4; ++m)
#pragma unroll
    for (int n = 0; n < 4; ++n)
#pragma unroll
      for (int j = 0; j < 4; ++j) {
        int r = brow + wr * 64 + m * 16 + fq * 4 + j;
        int c = bcol + wc * 64 + n * 16 + fr;
        int cc = c & 1023;
        float v = acc[m][n][j] + bp[cc];
        int b = r >> 9, s = r & 511;
        int hh = cc >> 6, d = cc & 63;
        size_t o = (((size_t)(b * 16 + hh)) * 512 + s) * 64 + d;
        outp[o] = f2bf(v);
      }
}

// ---------------- out-proj GEMM (XCD-grouped 1D grid, 512 blocks), bf16 xres out ----------------
__global__ __launch_bounds__(256)
void gemm_out(const u16* __restrict__ A, const u16* __restrict__ Bt,
              const float* __restrict__ bias, const float* __restrict__ resid,
              u16* __restrict__ outb) {
  const int K = 1024;
  __shared__ __align__(16) u16 As[64][32];
  __shared__ __align__(16) u16 Bs[128][32];
  int xcd = blockIdx.x & 7;
  int l = blockIdx.x >> 3;          // 0..63
  int tid = threadIdx.x, wid = tid >> 6, lane = tid & 63;
  int wr = wid >> 1, wc = wid & 1;
  int brow = l * 64, bcol = xcd * 128;
  int fr = lane & 15, fq = lane >> 4, k0 = fq * 8;
  int srow = lane >> 2;
  int sk = (lane & 3) * 8;

  f32x4 acc[2][4];
#pragma unroll
  for (int m = 0; m < 2; ++m)
#pragma unroll
    for (int n = 0; n < 4; ++n) acc[m][n] = (f32x4){0.f, 0.f, 0.f, 0.f};

  for (int kt = 0; kt < K; kt += 32) {
#pragma unroll
    for (int c = 0; c < 3; ++c) {
      int chunk = wid * 3 + c;
      if (chunk < 4)
        gload_lds16(A + (size_t)(brow + chunk * 16 + srow) * K + kt + sk,
                    (char*)As + chunk * 1024);
      else
        gload_lds16(Bt + (size_t)(bcol + (chunk - 4) * 16 + srow) * K + kt + sk,
                    (char*)Bs + (chunk - 4) * 1024);
    }
    __syncthreads();
    short8 afr[2], bfr[4];
#pragma unroll
    for (int m = 0; m < 2; ++m) afr[m] = *(const short8*)&As[wr * 32 + m * 16 + fr][k0];
#pragma unroll
    for (int n = 0; n < 4; ++n) bfr[n] = *(const short8*)&Bs[wc * 64 + n * 16 + fr][k0];
#pragma unroll
    for (int m = 0; m < 2; ++m)
#pragma unroll
      for (int n = 0; n < 4; ++n)
        acc[m][n] = mfma16(afr[m], bfr[n], acc[m][n]);
    __syncthreads();
  }

#pragma unroll
  for (int m = 0; m < 2; ++m)
#pragma unroll
    for (int n = 0; n < 4; ++n)
#pragma unroll
      for (int j = 0; j < 4; ++j) {
        int r = brow + wr * 32 + m * 16 + fq * 4 + j;
        int c = bcol + wc * 64 + n * 16 + fr;
        float v = acc[m][n][j] + bias[c] + resid[(size_t)r * 1024 + c];
        outb[(size_t)r * 1024 + c] = f2bf(v);
      }
}

// ---------------- attention: LDS-resident K/V via global_load_lds (pre-swizzled src) ----------------
// grid 512 x 256 thr (2 blocks/CU), XCD-grouped. Round-15 version.
__global__ __launch_bounds__(256, 2)
void attention(const u16* __restrict__ Q, const u16* __restrict__ K,
               const u16* __restrict__ Vt, const float* __restrict__ mask,
               float* __restrict__ score_out, u16* __restrict__ ctx) {
  const int S = 512, DH = 64;
  int bid = blockIdx.x;
  int xcd = bid & 7;
  int rest = bid >> 3;                 // 0..63
  int qq = rest & 3;                   // q-quarter
  int bh = xcd * 16 + (rest >> 2);     // XCD owns 16 bh
  int b = bh >> 4, h = bh & 15;
  int tid = threadIdx.x;
  int wid = tid >> 6, lane = tid & 63;
  int fr = lane & 15, fq = lane >> 4, k0e = fq * 8;
  int qbase = qq * 128 + wid * 32;

  const u16* Kp = K + (size_t)bh * S * DH;
  const u16* Vp = Vt + (size_t)bh * DH * S;
  const float* mrow = mask + b * S;

  __shared__ __align__(16) u16 Kl[256][64];   // phase keys, row-XOR-swizzled
  __shared__ __align__(16) u16 Vl[64][256];   // V^T phase cols, row-XOR-swizzled

  short8 af[2][2];
#pragma unroll
  for (int st = 0; st < 2; ++st) {
    const u16* Qp = Q + ((size_t)bh * S + qbase + st * 16 + fr) * DH;
    af[st][0] = *(const short8*)(Qp + k0e);
    af[st][1] = *(const short8*)(Qp + 32 + k0e);
  }

  float rsum[2] = {0.f, 0.f};
  f32x4 cacc[2][4];
#pragma unroll
  for (int st = 0; st < 2; ++st)
#pragma unroll
    for (int n = 0; n < 4; ++n) cacc[st][n] = (f32x4){0.f, 0.f, 0.f, 0.f};

  int hi = fq >> 1;
  int srcb = ((fq & 1) << 5) | fr;

#pragma unroll
  for (int p = 0; p < 2; ++p) {
    u32 mreg[16][2];
#pragma unroll
    for (int nb8 = 0; nb8 < 16; ++nb8) {
      float4 mv = *(const float4*)(mrow + p * 256 + nb8 * 16 + fq * 4);
      mreg[nb8][0] = pack2(mv.x * -10000.f, mv.y * -10000.f);
      mreg[nb8][1] = pack2(mv.z * -10000.f, mv.w * -10000.f);
    }
#pragma unroll
    for (int i = 0; i < 8; ++i) {
      int c = i * 256 + tid;
      int row = c >> 3, ch8 = c & 7;
      const u16* src = Kp + (size_t)(p * 256 + row) * 64 + 8 * (ch8 ^ (row & 7));
      gload_lds16(src, (char*)Kl + (i * 256 + wid * 64) * 16);
    }
#pragma unroll
    for (int i = 0; i < 8; ++i) {
      int c = i * 256 + tid;
      int d = c >> 5, ch = c & 31;
      const u16* src = Vp + (size_t)d * 512 + p * 256 + 8 * (ch ^ (d & 7));
      gload_lds16(src, (char*)Vl + (i * 256 + wid * 64) * 16);
    }
    __syncthreads();

#pragma unroll
    for (int st = 0; st < 2; ++st) {
      float* srow = score_out + ((size_t)(bh * 512 + qbase + st * 16 + fr)) * 512 + p * 256;
      u32 pk[16][2];
      __builtin_amdgcn_s_setprio(1);
#pragma unroll
      for (int nb8 = 0; nb8 < 16; ++nb8) {
        int r = nb8 * 16 + fr;
        int sw = (r & 7) << 3;
        short8 kf0 = *(const short8*)&Kl[r][k0e ^ sw];
        short8 kf1 = *(const short8*)&Kl[r][(32 + k0e) ^ sw];
        f32x4 a = (f32x4){0.f, 0.f, 0.f, 0.f};
        a = mfma16(kf0, af[st][0], a);
        a = mfma16(kf1, af[st][1], a);
        f32x4 s4;
        s4[0] = a[0] * 0.125f + bf2f((u16)(mreg[nb8][0] & 0xffff));
        s4[1] = a[1] * 0.125f + bf2f((u16)(mreg[nb8][0] >> 16));
        s4[2] = a[2] * 0.125f + bf2f((u16)(mreg[nb8][1] & 0xffff));
        s4[3] = a[3] * 0.125f + bf2f((u16)(mreg[nb8][1] >> 16));
        *(f32x4*)(srow + nb8 * 16 + fq * 4) = s4;
        float p0 = __expf(s4[0]);
        float p1 = __expf(s4[1]);
        float p2 = __expf(s4[2]);
        float p3 = __expf(s4[3]);
        rsum[st] += (p0 + p1) + (p2 + p3);
        pk[nb8][0] = pack2(p0, p1);
        pk[nb8][1] = pack2(p2, p3);
      }
#pragma unroll
      for (int ks = 0; ks < 8; ++ks) {
        u32 s0 = hi ? pk[2 * ks + 1][0] : pk[2 * ks][0];
        u32 s1 = hi ? pk[2 * ks + 1][1] : pk[2 * ks][1];
        u32x4 tv;
        tv.x = (u32)__shfl((int)s0, srcb, 64);
        tv.y = (u32)__shfl((int)s1, srcb, 64);
        tv.z = (u32)__shfl((int)s0, srcb + 16, 64);
        tv.w = (u32)__shfl((int)s1, srcb + 16, 64);
        short8 pa = __builtin_bit_cast(short8, tv);
        int kg = ks * 32 + k0e;
#pragma unroll
        for (int n = 0; n < 4; ++n) {
          int d = n * 16 + fr;
          short8 vf = *(const short8*)&Vl[d][kg ^ ((d & 7) << 3)];
          cacc[st][n] = mfma16(pa, vf, cacc[st][n]);
        }
      }
      __builtin_amdgcn_s_setprio(0);
    }
    __syncthreads();
  }

#pragma unroll
  for (int st = 0; st < 2; ++st) {
    rsum[st] += __shfl_xor(rsum[st], 16, 64);
    rsum[st] += __shfl_xor(rsum[st], 32, 64);
    float inv = 1.0f / rsum[st];
#pragma unroll
    for (int j = 0; j < 4; ++j) {
      float invj = __shfl(inv, (lane & 48) | ((fq * 4 + j) & 15), 64);
      int q = qbase + st * 16 + fq * 4 + j;
#pragma unroll
      for (int n = 0; n < 4; ++n) {
        float v = cacc[st][n][j] * invj;
        int d = n * 16 + fr;
        ctx[((size_t)(b * 512 + q)) * 1024 + h * 64 + d] = f2bf(v);
      }
    }
  }
}

// ---------------- LayerNorm (bf16 input) ----------------
__global__ __launch_bounds__(256)
void ln_kernel(const u16* __restrict__ x, const float* __restrict__ g,
               const float* __restrict__ be, float* __restrict__ out) {
  int row = blockIdx.x, t = threadIdx.x;
  uint2 w = *(const uint2*)(x + (size_t)row * 1024 + t * 4);
  float v0 = bf2f((u16)(w.x & 0xffff));
  float v1 = bf2f((u16)(w.x >> 16));
  float v2 = bf2f((u16)(w.y & 0xffff));
  float v3 = bf2f((u16)(w.y >> 16));
  float s = (v0 + v1) + (v2 + v3);
  float s2 = (v0 * v0 + v1 * v1) + (v2 * v2 + v3 * v3);
#pragma unroll
  for (int o = 1; o < 64; o <<= 1) {
    s += __shfl_xor(s, o, 64);
    s2 += __shfl_xor(s2, o, 64);
  }
  __shared__ float ls[4], ls2[4];
  int wv = t >> 6;
  if ((t & 63) == 0) { ls[wv] = s; ls2[wv] = s2; }
  __syncthreads();
  float S = ls[0] + ls[1] + ls[2] + ls[3];
  float S2 = ls2[0] + ls2[1] + ls2[2] + ls2[3];
  float mu = S * (1.0f / 1024.0f);
  float var = S2 * (1.0f / 1024.0f) - mu * mu;
  float r = rsqrtf(var + 1e-5f);
  float4 gv = ((const float4*)g)[t];
  float4 bv = ((const float4*)be)[t];
  float4 o4;
  o4.x = gv.x * (v0 - mu) * r + bv.x;
  o4.y = gv.y * (v1 - mu) * r + bv.y;
  o4.z = gv.z * (v2 - mu) * r + bv.z;
  o4.w = gv.w * (v3 - mu) * r + bv.w;
  ((float4*)(out + (size_t)row * 1024))[t] = o4;
}

// ---------------- launch ----------------
extern "C" void kernel_launch(void* const* d_in, const int* in_sizes, int n_in,
                              void* d_out, int out_size, void* d_ws, size_t ws_size,
                              hipStream_t stream) {
  const float* hidden = (const float*)d_in[0];
  const float* mask   = (const float*)d_in[1];
  const float* Wq = (const float*)d_in[2];  const float* bq = (const float*)d_in[3];
  const float* Wk = (const float*)d_in[4];  const float* bk = (const float*)d_in[5];
  const float* Wv = (const float*)d_in[6];  const float* bv = (const float*)d_in[7];
  const float* Wo = (const float*)d_in[8];  const float* bo = (const float*)d_in[9];
  const float* gamma = (const float*)d_in[10];
  const float* beta  = (const float*)d_in[11];

  float* out = (float*)d_out;
  float* attn_out = out + 4194304;  // [B][H][S][S]

  char* ws = (char*)d_ws;
  u16* hbf    = (u16*)(ws);                 // [4096][1024] bf16
  u16* WqkvT  = (u16*)(ws + 8388608);       // [3072][1024] bf16 (fused)
  u16* WoT    = (u16*)(ws + 14680064);      // [1024][1024] bf16
  u16* Qb     = (u16*)(ws + 16777216);      // [B][H][S][DH]
  u16* Kb     = (u16*)(ws + 25165824);      // [B][H][S][DH]
  u16* Vb     = (u16*)(ws + 33554432);      // [B][H][S][DH]
  u16* Vt     = (u16*)(ws + 41943040);      // [B][H][DH][S]
  u16* ctx    = (u16*)(ws + 50331648);      // [4096][1024]
  u16* xres   = (u16*)(ws + 16777216);      // [4096][1024] bf16 (reuses Qb, dead after attention)

  prep<<<dim3(32, 32, 5), dim3(32, 8), 0, stream>>>(
      Wq, Wk, Wv, Wo, hidden,
      WqkvT, WqkvT + 1048576, WqkvT + 2097152, WoT, hbf);
  gemm_qkv<<<768, 256, 0, stream>>>(hbf, WqkvT, bq, bk, bv, Qb, Kb, Vb);
  vtrans<<<dim3(16, 2, 128), dim3(32, 8), 0, stream>>>(Vb, Vt);
  attention<<<512, 256, 0, stream>>>(Qb, Kb, Vt, mask, attn_out, ctx);
  gemm_out<<<512, 256, 0, stream>>>(ctx, WoT, bo, hidden, xres);
  ln_kernel<<<4096, 256, 0, stream>>>(xres, gamma, beta, out);
}